// Round 14
// baseline (33.054 us; speedup 1.0000x reference)
//
#include <hip/hip_runtime.h>

// QuerySpecificClusterModel: B=256 samples, n=64 points, d=768.
// Round 14: (a) re-split gram/cluster for per-phase ground truth (round-13's
// null result exposed that my 13/17us phase split rests on one derived
// counter; shuffles turned out to share the DS pipe's ~120cyc latency with
// the LDS ops they replaced). (b) 4-pass Gram: drop hl/lh terms (error
// ~3e-6/distance, same order as the reference's own fp32 noise under which
// absmax has been 0.0 for 13 rounds) -> 1/3 less LDS fragment traffic,
// 1/3 less staging VALU, MFMA 6->4 passes, Hml 96->64 KB.

#define NPTS 64
#define DIM 768
#define CH 128
#define NCH 6
#define NT 512
#define BIGF 1e9f
#define PGS 68

typedef __attribute__((ext_vector_type(8))) __bf16 bf16x8;
typedef __attribute__((ext_vector_type(4))) float f32x4;
typedef __attribute__((ext_vector_type(8))) unsigned short us8;

// cross-lane LDS visibility fence within one wave (guide rule #18)
__device__ __forceinline__ void lds_fence() {
  asm volatile("s_waitcnt lgkmcnt(0)" ::: "memory");
  __builtin_amdgcn_sched_barrier(0);
}

// ---- 2-way bf16 split: x ~= h + m (residual ~2^-18 |x| dropped) ----
__device__ __forceinline__ void split2(float x, unsigned short& h,
                                       unsigned short& m) {
  unsigned u = __float_as_uint(x);
  unsigned rb = (u + 0x7FFFu + ((u >> 16) & 1u)) & 0xFFFF0000u;   // RNE
  h = (unsigned short)(rb >> 16);
  float r1 = x - __uint_as_float(rb);                              // exact
  unsigned u1 = __float_as_uint(r1);
  unsigned rb1 = (u1 + 0x7FFFu + ((u1 >> 16) & 1u)) & 0xFFFF0000u;
  m = (unsigned short)(rb1 >> 16);
}

// 64-lane match mask of a 6-bit value held per-lane (6 ballots, all VALU)
__device__ __forceinline__ unsigned long long match6(int v) {
  unsigned long long m = ~0ull;
  #pragma unroll
  for (int bb = 0; bb < 6; ++bb) {
    unsigned long long mb = __ballot(((v >> bb) & 1) != 0);
    m &= (((v >> bb) & 1) != 0) ? mb : ~mb;
  }
  return m;
}

// stage one chunk (scale by q, split2, swizzled LDS write). Hb = Hml[buf].
__device__ __forceinline__ void stage_chunk(
    unsigned short (*Hb)[NPTS][CH], const float4 (&pva)[2][2],
    const float4 (&qv)[2], int row0, int gran) {
  #pragma unroll
  for (int rr = 0; rr < 2; ++rr) {
    const int row = row0 + (rr << 5);
    float xs[8];
    xs[0] = pva[rr][0].x * qv[0].x; xs[1] = pva[rr][0].y * qv[0].y;
    xs[2] = pva[rr][0].z * qv[0].z; xs[3] = pva[rr][0].w * qv[0].w;
    xs[4] = pva[rr][1].x * qv[1].x; xs[5] = pva[rr][1].y * qv[1].y;
    xs[6] = pva[rr][1].z * qv[1].z; xs[7] = pva[rr][1].w * qv[1].w;
    us8 uh, um;
    #pragma unroll
    for (int e = 0; e < 8; ++e) {
      unsigned short hh, mm;
      split2(xs[e], hh, mm);
      uh[e] = hh; um[e] = mm;
    }
    const int p = gran ^ (row & 15);
    *reinterpret_cast<us8*>(&Hb[0][row][p << 3]) = uh;
    *reinterpret_cast<us8*>(&Hb[1][row][p << 3]) = um;
  }
}

// one chunk of MFMA work for this wave (4 passes: hh, hm, mh, mm).
__device__ __forceinline__ void mfma_chunk(
    const unsigned short (*Hb)[NPTS][CH], f32x4 (&acc)[2][2],
    int R, int C, int ksub, int lrow, int lhi) {
  #pragma unroll 1
  for (int ss = 0; ss < 2; ++ss) {
    const int s = ksub + (ss << 1);
    const int p = ((s << 2) + lhi) ^ lrow;
    bf16x8 fa[2][2], fb[2][2];
    #pragma unroll
    for (int v = 0; v < 2; ++v)
      #pragma unroll
      for (int tb = 0; tb < 2; ++tb) {
        const int row = (R << 5) + (tb << 4) + lrow;
        fa[v][tb] = *reinterpret_cast<const bf16x8*>(&Hb[v][row][p << 3]);
      }
    if (R != C) {
      #pragma unroll
      for (int v = 0; v < 2; ++v)
        #pragma unroll
        for (int tb = 0; tb < 2; ++tb) {
          const int row = (C << 5) + (tb << 4) + lrow;
          fb[v][tb] = *reinterpret_cast<const bf16x8*>(&Hb[v][row][p << 3]);
        }
    } else {
      #pragma unroll
      for (int v = 0; v < 2; ++v)
        #pragma unroll
        for (int tb = 0; tb < 2; ++tb) fb[v][tb] = fa[v][tb];
    }
    #pragma unroll
    for (int ti = 0; ti < 2; ++ti)
      #pragma unroll
      for (int tj = 0; tj < 2; ++tj) {
        acc[ti][tj] = __builtin_amdgcn_mfma_f32_16x16x32_bf16(fa[0][ti], fb[0][tj], acc[ti][tj], 0, 0, 0); // hh
        acc[ti][tj] = __builtin_amdgcn_mfma_f32_16x16x32_bf16(fa[0][ti], fb[1][tj], acc[ti][tj], 0, 0, 0); // hm
        acc[ti][tj] = __builtin_amdgcn_mfma_f32_16x16x32_bf16(fa[1][ti], fb[0][tj], acc[ti][tj], 0, 0, 0); // mh
        acc[ti][tj] = __builtin_amdgcn_mfma_f32_16x16x32_bf16(fa[1][ti], fb[1][tj], acc[ti][tj], 0, 0, 0); // mm
      }
  }
}

#define ISSUE_P(PV, cix) do {                                       \
    const int off_ = (cix) * CH;                                    \
    PV[0][0] = *(const float4*)(pr0 + off_);                        \
    PV[0][1] = *(const float4*)(pr0 + off_ + 4);                    \
    PV[1][0] = *(const float4*)(pr1 + off_);                        \
    PV[1][1] = *(const float4*)(pr1 + off_ + 4);                    \
  } while (0)

#define ISSUE_Q(QV, cix) do {                                       \
    const int off_ = (cix) * CH;                                    \
    QV[0] = *(const float4*)(qr + off_);                            \
    QV[1] = *(const float4*)(qr + off_ + 4);                        \
  } while (0)

// ================= kernel A: MFMA Gram + distances -> Dg ====================
__global__ __launch_bounds__(NT) void gram_kernel(
    const float* __restrict__ q,      // [256,768]
    const float* __restrict__ psg,    // [256,64,768]
    float* __restrict__ Dg)           // [256,64,64]
{
  __shared__ __align__(16) unsigned short Hml[2][2][NPTS][CH]; // 64 KB dbuf
  __shared__ __align__(16) float PG[NPTS * PGS];
  __shared__ float diagf[NPTS];

  const int b = blockIdx.x;
  const int t = threadIdx.x;
  const int w = t >> 6;
  const int l = t & 63;

  const float* qb = q + (size_t)b * DIM;
  const float* pb = psg + (size_t)b * NPTS * DIM;

  const int row0 = t >> 4;
  const int gran = t & 15;
  const float* pr0 = pb + (size_t)row0 * DIM + (gran << 3);
  const float* pr1 = pr0 + 32 * DIM;
  const float* qr  = qb + (gran << 3);

  const int rw = w >> 1;
  const int R = rw >> 1, C = rw & 1;
  const int ksub = w & 1;
  const int lrow = l & 15;
  const int lhi  = l >> 4;

  f32x4 acc[2][2];
  {
    f32x4 z = {0.f, 0.f, 0.f, 0.f};
    acc[0][0] = z; acc[0][1] = z; acc[1][0] = z; acc[1][1] = z;
  }

  float4 pvaA[2][2], pvaB[2][2], qv[2];

  ISSUE_P(pvaA, 0);
  ISSUE_Q(qv, 0);
  ISSUE_P(pvaB, 1);
  stage_chunk(Hml[0], pvaA, qv, row0, gran);
  __syncthreads();

  #pragma unroll 1
  for (int cc = 0; cc < 3; ++cc) {
    if (cc < 2) ISSUE_P(pvaA, 2 * cc + 2);
    ISSUE_Q(qv, 2 * cc + 1);
    mfma_chunk(Hml[0], acc, R, C, ksub, lrow, lhi);
    stage_chunk(Hml[1], pvaB, qv, row0, gran);
    __syncthreads();
    if (cc < 2) {
      ISSUE_P(pvaB, 2 * cc + 3);
      ISSUE_Q(qv, 2 * cc + 2);
    }
    mfma_chunk(Hml[1], acc, R, C, ksub, lrow, lhi);
    if (cc < 2) stage_chunk(Hml[0], pvaA, qv, row0, gran);
    __syncthreads();
  }

  // ---- K-split pair reduce: odd wave -> LDS, even wave adds ----
  if (w & 1) {
    float* dst = PG + (rw << 10);
    #pragma unroll
    for (int ti = 0; ti < 2; ++ti)
      #pragma unroll
      for (int tj = 0; tj < 2; ++tj)
        *reinterpret_cast<f32x4*>(dst + (((ti << 1) + tj) << 8) + (l << 2)) = acc[ti][tj];
  }
  __syncthreads();
  if (!(w & 1)) {
    const float* src = PG + (rw << 10);
    #pragma unroll
    for (int ti = 0; ti < 2; ++ti)
      #pragma unroll
      for (int tj = 0; tj < 2; ++tj)
        acc[ti][tj] += *reinterpret_cast<const f32x4*>(src + (((ti << 1) + tj) << 8) + (l << 2));
  }
  __syncthreads();
  if (!(w & 1)) {
    #pragma unroll
    for (int ti = 0; ti < 2; ++ti)
      #pragma unroll
      for (int tj = 0; tj < 2; ++tj)
        #pragma unroll
        for (int reg = 0; reg < 4; ++reg) {
          const int grow = (R << 5) + (ti << 4) + (lhi << 2) + reg;
          const int gcol = (C << 5) + (tj << 4) + lrow;
          PG[grow * PGS + gcol] = acc[ti][tj][reg];
        }
  }
  __syncthreads();

  // ---- distances -> global Dg (coalesced float4 stores) ----
  if (t < NPTS) diagf[t] = PG[t * PGS + t];
  __syncthreads();
  {
    const int r  = t >> 3;
    const int c0 = (t & 7) << 3;
    const float dr = diagf[r];
    float vout[8];
    #pragma unroll
    for (int e = 0; e < 8; ++e) {
      const int cc = c0 + e;
      const float gg = PG[r * PGS + cc];
      float d2 = dr + diagf[cc] - 2.f * gg;
      d2 = fmaxf(d2, 0.f);
      vout[e] = (d2 > 0.f) ? sqrtf(d2) : 0.f;
    }
    float* Db = Dg + (size_t)b * NPTS * NPTS;
    *(float4*)(Db + (r << 6) + c0)     = make_float4(vout[0], vout[1], vout[2], vout[3]);
    *(float4*)(Db + (r << 6) + c0 + 4) = make_float4(vout[4], vout[5], vout[6], vout[7]);
  }
}

// ============== kernel B: register-Boruvka clustering (round 13) ============
__global__ __launch_bounds__(64) void cluster_kernel(
    const float* __restrict__ Dg,     // [256,64,64]
    const int*   __restrict__ labels, // [256,64]
    float* __restrict__ simS_o, float* __restrict__ disS_o,
    int* __restrict__ simC_o, int* __restrict__ errC_o)
{
  __shared__ unsigned bw_s[NPTS], bfl_s[NPTS];
  __shared__ int lab_s[NPTS];
  __shared__ __align__(8) unsigned long long ekey_s[NPTS];

  const int b = blockIdx.x;
  const int l = threadIdx.x;
  const float* Db = Dg + (size_t)b * NPTS * NPTS;

  // own row into registers (global, L2/L3-hot, 16 pipelined float4 loads)
  float drow[64];
  #pragma unroll
  for (int v4 = 0; v4 < 16; ++v4) {
    float4 x = *reinterpret_cast<const float4*>(Db + (l << 6) + (v4 << 2));
    drow[v4 * 4 + 0] = x.x; drow[v4 * 4 + 1] = x.y;
    drow[v4 * 4 + 2] = x.z; drow[v4 * 4 + 3] = x.w;
  }
  int tl = labels[b * NPTS + l];

  unsigned long long sMask = 0ull;
  int kcnt = 0;
  #pragma unroll
  for (int v = 0; v < 8; ++v) {
    unsigned long long mv = __ballot(tl == v);
    kcnt += (mv != 0ull) ? 1 : 0;
    if (tl == v) sMask = mv;
  }
  int simC = __popcll(sMask);
  const int merges = NPTS - kcnt;

  float simS = 0.f, disS = 0.f;
  #pragma unroll
  for (int j = 0; j < NPTS; ++j) {
    bool sim = (sMask >> j) & 1ull;
    simS += sim ? drow[j] : 0.f;
    disS += sim ? 0.f : drow[j];
  }

  // ---- register-resident Boruvka ----
  unsigned long long same = 1ull << l;
  int repSlot = l;
  int ecnt = 0;

  #pragma unroll 1
  for (int rd = 0; rd < 6; ++rd) {
    bw_s[l] = 0xFFFFFFFFu; bfl_s[l] = 0xFFFFFFFFu;
    lds_fence();
    float bv = BIGF; int bj = 64;
    #pragma unroll
    for (int j = 0; j < NPTS; ++j) {
      bool ok = !((same >> j) & 1ull) && (drow[j] < bv);
      bv = ok ? drow[j] : bv;
      bj = ok ? j : bj;
    }
    if (bj < 64) atomicMin(&bw_s[repSlot], __float_as_uint(bv));
    lds_fence();
    const unsigned bwc = bw_s[repSlot];
    if (bj < 64 && __float_as_uint(bv) == bwc)
      atomicMin(&bfl_s[repSlot], (unsigned)((l << 6) | bj));
    lds_fence();
    const unsigned rfl = bfl_s[repSlot];
    const bool valid = (bwc != 0xFFFFFFFFu);
    const int vpt = (int)(rfl & 63);
    const int otherRep = __shfl(repSlot, vpt);
    const bool isRoot = (l == repSlot);
    int ptr = repSlot;
    if (isRoot && valid) ptr = otherRep;
    const int pd = __shfl(ptr, ptr);
    bool adder = false;
    if (isRoot && valid && ptr != l) {
      if (pd == l && l < ptr) ptr = l;
      else adder = true;
    }
    const unsigned long long A = __ballot(adder);
    if (adder)
      ekey_s[ecnt + __popcll(A & ((1ull << l) - 1ull))] =
          ((unsigned long long)bwc << 12) | (unsigned long long)rfl;
    ecnt += (int)__popcll(A);
    #pragma unroll 1
    for (int jj = 0; jj < 6; ++jj) {
      const int p2 = __shfl(ptr, ptr);
      if (__ballot(p2 != ptr) == 0ull) break;
      ptr = p2;
    }
    same = match6(ptr);
    repSlot = __ffsll((long long)same) - 1;
    if (same == ~0ull) break;
  }
  lds_fence();

  // ---- edge selection: keep the `merges` smallest (w, flat) keys ----
  const bool ehave = (l < ecnt);
  const unsigned long long my = ehave ? ekey_s[l] : ~0ull;
  int rank = 0;
  #pragma unroll 7
  for (int j = 0; j < 63; ++j) {
    unsigned long long kj = ekey_s[j];
    rank += (j < ecnt && kj < my) ? 1 : 0;
  }
  const bool kept = ehave && (rank < merges);
  const int eu = (int)((my >> 6) & 63);
  const int ev = (int)(my & 63);

  // ---- label propagation: edge relax + pointer doubling ----
  lab_s[l] = l;
  lds_fence();
  #pragma unroll 1
  for (int iter = 0; iter < 64; ++iter) {
    int m = 0; bool ch = false;
    if (kept) {
      const int lu = lab_s[eu], lv = lab_s[ev];
      m = min(lu, lv);
      ch = (m < lu) || (m < lv);
    }
    if (ch) {
      atomicMin(&lab_s[eu], m);
      atomicMin(&lab_s[ev], m);
    }
    lds_fence();
    const int la = lab_s[l];
    const int lb = lab_s[la];
    if (lb < la) lab_s[l] = lb;
    lds_fence();
    if (__ballot(ch) == 0ull) break;
  }
  const int cl = lab_s[l];

  const unsigned long long cMask = match6(cl);
  int ec2 = __popcll(cMask ^ sMask);

  #pragma unroll
  for (int off = 32; off; off >>= 1) {
    simS += __shfl_xor(simS, off);
    disS += __shfl_xor(disS, off);
    simC += __shfl_xor(simC, off);
    ec2  += __shfl_xor(ec2, off);
  }
  if (l == 0) {
    simS_o[b] = simS; disS_o[b] = disS;
    simC_o[b] = simC; errC_o[b] = ec2;
  }
}

__global__ __launch_bounds__(64) void finalize_kernel(
    const float* __restrict__ simS, const float* __restrict__ disS,
    const int* __restrict__ simC, const int* __restrict__ errC,
    float* __restrict__ out)
{
  const int l = threadIdx.x;
  double ss = 0.0, dd = 0.0, sc = 0.0, ec = 0.0;
  #pragma unroll
  for (int r = 0; r < 4; ++r) {
    int i = (r << 6) + l;
    ss += (double)simS[i];
    dd += (double)disS[i];
    sc += (double)simC[i];
    ec += (double)errC[i];
  }
  #pragma unroll
  for (int off = 32; off; off >>= 1) {
    ss += __shfl_xor(ss, off);
    dd += __shfl_xor(dd, off);
    sc += __shfl_xor(sc, off);
    ec += __shfl_xor(ec, off);
  }
  if (l == 0) {
    const double total = 256.0 * 4096.0;
    double ms = ss / sc;
    double md = dd / (total - sc);
    out[0] = (float)(ec / 256.0 + 0.5 * (ms - md));
  }
}

extern "C" void kernel_launch(void* const* d_in, const int* in_sizes, int n_in,
                              void* d_out, int out_size, void* d_ws, size_t ws_size,
                              hipStream_t stream) {
  const float* q      = (const float*)d_in[0];
  const float* psg    = (const float*)d_in[1];
  const int*   labels = (const int*)d_in[2];
  float* out = (float*)d_out;

  float* Dg   = (float*)d_ws;              // [256*64*64] = 4 MB
  float* simS = Dg + 256 * NPTS * NPTS;    // [256]
  float* disS = simS + 256;                // [256]
  int*   simC = (int*)(disS + 256);        // [256]
  int*   errC = simC + 256;                // [256]

  gram_kernel<<<256, NT, 0, stream>>>(q, psg, Dg);
  cluster_kernel<<<256, 64, 0, stream>>>(Dg, labels, simS, disS, simC, errC);
  finalize_kernel<<<1, 64, 0, stream>>>(simS, disS, simC, errC, out);
}

// Round 15
// 31.786 us; speedup vs baseline: 1.0399x; 1.0399x over previous
//
#include <hip/hip_runtime.h>

// QuerySpecificClusterModel: B=256 samples, n=64 points, d=768.
// Round 15: fused (round 13) + 4-pass gram (round 14, absmax-0-validated) +
// ALL-BALLOT Boruvka tail. Round-13 lesson: shfl shares the DS pipe's
// ~120-250cyc latency with LDS; ballot is VALU-cheap. All tail values are
// <=6 bits -> rebuild every cross-lane op on ballots: per-comp min via
// 32-step radix ballot (exact (w, lowest-flat), replaces atomicMin+3 fences),
// publish6/extract6 gather replaces every shfl (rep/endpoint/ptr-doubling).
// Only DS left in tail: ekey_s writes + 1 fence + short LDS label prop.

#define NPTS 64
#define DIM 768
#define CH 128
#define NCH 6
#define NT 512
#define BIGF 1e9f
#define PGS 68

typedef __attribute__((ext_vector_type(8))) __bf16 bf16x8;
typedef __attribute__((ext_vector_type(4))) float f32x4;
typedef __attribute__((ext_vector_type(8))) unsigned short us8;

__device__ __forceinline__ void lds_fence() {
  asm volatile("s_waitcnt lgkmcnt(0)" ::: "memory");
  __builtin_amdgcn_sched_barrier(0);
}

// ---- 2-way bf16 split: x ~= h + m (residual ~2^-18|x| dropped; validated) --
__device__ __forceinline__ void split2(float x, unsigned short& h,
                                       unsigned short& m) {
  unsigned u = __float_as_uint(x);
  unsigned rb = (u + 0x7FFFu + ((u >> 16) & 1u)) & 0xFFFF0000u;   // RNE
  h = (unsigned short)(rb >> 16);
  float r1 = x - __uint_as_float(rb);                              // exact
  unsigned u1 = __float_as_uint(r1);
  unsigned rb1 = (u1 + 0x7FFFu + ((u1 >> 16) & 1u)) & 0xFFFF0000u;
  m = (unsigned short)(rb1 >> 16);
}

// ---- ballot-gather of 6-bit per-lane values (all VALU/SALU, no DS) ----
__device__ __forceinline__ void publish6(int v, unsigned long long (&m)[6]) {
  #pragma unroll
  for (int k = 0; k < 6; ++k) m[k] = __ballot(((v >> k) & 1) != 0);
}
__device__ __forceinline__ int extract6(const unsigned long long (&m)[6], int p) {
  int r = 0;
  #pragma unroll
  for (int k = 0; k < 6; ++k) r |= (int)((m[k] >> p) & 1ull) << k;
  return r;
}
__device__ __forceinline__ unsigned long long match6(int v) {
  unsigned long long m = ~0ull;
  #pragma unroll
  for (int bb = 0; bb < 6; ++bb) {
    unsigned long long mb = __ballot(((v >> bb) & 1) != 0);
    m &= (((v >> bb) & 1) != 0) ? mb : ~mb;
  }
  return m;
}

// stage one chunk (scale by q, split2, swizzled LDS write). Hb = Hml[buf].
__device__ __forceinline__ void stage_chunk(
    unsigned short (*Hb)[NPTS][CH], const float4 (&pva)[2][2],
    const float4 (&qv)[2], int row0, int gran) {
  #pragma unroll
  for (int rr = 0; rr < 2; ++rr) {
    const int row = row0 + (rr << 5);
    float xs[8];
    xs[0] = pva[rr][0].x * qv[0].x; xs[1] = pva[rr][0].y * qv[0].y;
    xs[2] = pva[rr][0].z * qv[0].z; xs[3] = pva[rr][0].w * qv[0].w;
    xs[4] = pva[rr][1].x * qv[1].x; xs[5] = pva[rr][1].y * qv[1].y;
    xs[6] = pva[rr][1].z * qv[1].z; xs[7] = pva[rr][1].w * qv[1].w;
    us8 uh, um;
    #pragma unroll
    for (int e = 0; e < 8; ++e) {
      unsigned short hh, mm;
      split2(xs[e], hh, mm);
      uh[e] = hh; um[e] = mm;
    }
    const int p = gran ^ (row & 15);
    *reinterpret_cast<us8*>(&Hb[0][row][p << 3]) = uh;
    *reinterpret_cast<us8*>(&Hb[1][row][p << 3]) = um;
  }
}

// one chunk of MFMA work (4 passes: hh, hm, mh, mm).
__device__ __forceinline__ void mfma_chunk(
    const unsigned short (*Hb)[NPTS][CH], f32x4 (&acc)[2][2],
    int R, int C, int ksub, int lrow, int lhi) {
  #pragma unroll 1
  for (int ss = 0; ss < 2; ++ss) {
    const int s = ksub + (ss << 1);
    const int p = ((s << 2) + lhi) ^ lrow;
    bf16x8 fa[2][2], fb[2][2];
    #pragma unroll
    for (int v = 0; v < 2; ++v)
      #pragma unroll
      for (int tb = 0; tb < 2; ++tb) {
        const int row = (R << 5) + (tb << 4) + lrow;
        fa[v][tb] = *reinterpret_cast<const bf16x8*>(&Hb[v][row][p << 3]);
      }
    if (R != C) {
      #pragma unroll
      for (int v = 0; v < 2; ++v)
        #pragma unroll
        for (int tb = 0; tb < 2; ++tb) {
          const int row = (C << 5) + (tb << 4) + lrow;
          fb[v][tb] = *reinterpret_cast<const bf16x8*>(&Hb[v][row][p << 3]);
        }
    } else {
      #pragma unroll
      for (int v = 0; v < 2; ++v)
        #pragma unroll
        for (int tb = 0; tb < 2; ++tb) fb[v][tb] = fa[v][tb];
    }
    #pragma unroll
    for (int ti = 0; ti < 2; ++ti)
      #pragma unroll
      for (int tj = 0; tj < 2; ++tj) {
        acc[ti][tj] = __builtin_amdgcn_mfma_f32_16x16x32_bf16(fa[0][ti], fb[0][tj], acc[ti][tj], 0, 0, 0); // hh
        acc[ti][tj] = __builtin_amdgcn_mfma_f32_16x16x32_bf16(fa[0][ti], fb[1][tj], acc[ti][tj], 0, 0, 0); // hm
        acc[ti][tj] = __builtin_amdgcn_mfma_f32_16x16x32_bf16(fa[1][ti], fb[0][tj], acc[ti][tj], 0, 0, 0); // mh
        acc[ti][tj] = __builtin_amdgcn_mfma_f32_16x16x32_bf16(fa[1][ti], fb[1][tj], acc[ti][tj], 0, 0, 0); // mm
      }
  }
}

#define ISSUE_P(PV, cix) do {                                       \
    const int off_ = (cix) * CH;                                    \
    PV[0][0] = *(const float4*)(pr0 + off_);                        \
    PV[0][1] = *(const float4*)(pr0 + off_ + 4);                    \
    PV[1][0] = *(const float4*)(pr1 + off_);                        \
    PV[1][1] = *(const float4*)(pr1 + off_ + 4);                    \
  } while (0)

#define ISSUE_Q(QV, cix) do {                                       \
    const int off_ = (cix) * CH;                                    \
    QV[0] = *(const float4*)(qr + off_);                            \
    QV[1] = *(const float4*)(qr + off_ + 4);                        \
  } while (0)

// ============ fused kernel: MFMA Gram -> distances -> MST clustering ========
__global__ __launch_bounds__(NT) void fused_kernel(
    const float* __restrict__ q,      // [256,768]
    const float* __restrict__ psg,    // [256,64,768]
    const int*   __restrict__ labels, // [256,64]
    float* __restrict__ simS_o, float* __restrict__ disS_o,
    int* __restrict__ simC_o, int* __restrict__ errC_o)
{
  __shared__ __align__(16) unsigned short Hml[2][2][NPTS][CH]; // 64 KB dbuf
  __shared__ __align__(16) float PG[NPTS * PGS];
  __shared__ float diagf[NPTS];
  __shared__ int lab_s[NPTS];
  __shared__ __align__(8) unsigned long long ekey_s[NPTS];

  const int b = blockIdx.x;
  const int t = threadIdx.x;
  const int w = t >> 6;
  const int l = t & 63;

  const float* qb = q + (size_t)b * DIM;
  const float* pb = psg + (size_t)b * NPTS * DIM;

  const int row0 = t >> 4;
  const int gran = t & 15;
  const float* pr0 = pb + (size_t)row0 * DIM + (gran << 3);
  const float* pr1 = pr0 + 32 * DIM;
  const float* qr  = qb + (gran << 3);

  const int rw = w >> 1;
  const int R = rw >> 1, C = rw & 1;
  const int ksub = w & 1;
  const int lrow = l & 15;
  const int lhi  = l >> 4;

  f32x4 acc[2][2];
  {
    f32x4 z = {0.f, 0.f, 0.f, 0.f};
    acc[0][0] = z; acc[0][1] = z; acc[1][0] = z; acc[1][1] = z;
  }

  float4 pvaA[2][2], pvaB[2][2], qv[2];

  ISSUE_P(pvaA, 0);
  ISSUE_Q(qv, 0);
  ISSUE_P(pvaB, 1);
  stage_chunk(Hml[0], pvaA, qv, row0, gran);
  __syncthreads();

  #pragma unroll 1
  for (int cc = 0; cc < 3; ++cc) {
    if (cc < 2) ISSUE_P(pvaA, 2 * cc + 2);
    ISSUE_Q(qv, 2 * cc + 1);
    mfma_chunk(Hml[0], acc, R, C, ksub, lrow, lhi);
    stage_chunk(Hml[1], pvaB, qv, row0, gran);
    __syncthreads();
    if (cc < 2) {
      ISSUE_P(pvaB, 2 * cc + 3);
      ISSUE_Q(qv, 2 * cc + 2);
    }
    mfma_chunk(Hml[1], acc, R, C, ksub, lrow, lhi);
    if (cc < 2) stage_chunk(Hml[0], pvaA, qv, row0, gran);
    __syncthreads();
  }

  // ---- K-split pair reduce: odd wave -> LDS, even wave adds ----
  if (w & 1) {
    float* dst = PG + (rw << 10);
    #pragma unroll
    for (int ti = 0; ti < 2; ++ti)
      #pragma unroll
      for (int tj = 0; tj < 2; ++tj)
        *reinterpret_cast<f32x4*>(dst + (((ti << 1) + tj) << 8) + (l << 2)) = acc[ti][tj];
  }
  __syncthreads();
  if (!(w & 1)) {
    const float* src = PG + (rw << 10);
    #pragma unroll
    for (int ti = 0; ti < 2; ++ti)
      #pragma unroll
      for (int tj = 0; tj < 2; ++tj)
        acc[ti][tj] += *reinterpret_cast<const f32x4*>(src + (((ti << 1) + tj) << 8) + (l << 2));
  }
  __syncthreads();
  if (!(w & 1)) {
    #pragma unroll
    for (int ti = 0; ti < 2; ++ti)
      #pragma unroll
      for (int tj = 0; tj < 2; ++tj)
        #pragma unroll
        for (int reg = 0; reg < 4; ++reg) {
          const int grow = (R << 5) + (ti << 4) + (lhi << 2) + reg;
          const int gcol = (C << 5) + (tj << 4) + lrow;
          PG[grow * PGS + gcol] = acc[ti][tj][reg];
        }
  }
  __syncthreads();

  // ---- distances in place ----
  if (t < NPTS) diagf[t] = PG[t * PGS + t];
  __syncthreads();
  {
    const int r  = t >> 3;
    const int c0 = (t & 7) << 3;
    const float dr = diagf[r];
    #pragma unroll
    for (int e = 0; e < 8; ++e) {
      const int cc = c0 + e;
      const float gg = PG[r * PGS + cc];
      float d2 = dr + diagf[cc] - 2.f * gg;
      d2 = fmaxf(d2, 0.f);
      PG[r * PGS + cc] = (d2 > 0.f) ? sqrtf(d2) : 0.f;
    }
  }
  __syncthreads();
  if (w != 0) return;            // wave 0 runs the MST tail

  // ============== all-ballot Boruvka (single wave, lane l = point l) ========
  float drow[64];
  #pragma unroll
  for (int v4 = 0; v4 < 16; ++v4) {
    f32x4 x = *reinterpret_cast<const f32x4*>(&PG[l * PGS + (v4 << 2)]);
    drow[v4 * 4 + 0] = x[0]; drow[v4 * 4 + 1] = x[1];
    drow[v4 * 4 + 2] = x[2]; drow[v4 * 4 + 3] = x[3];
  }
  int tl = labels[b * NPTS + l];

  unsigned long long sMask = 0ull;
  int kcnt = 0;
  #pragma unroll
  for (int v = 0; v < 8; ++v) {
    unsigned long long mv = __ballot(tl == v);
    kcnt += (mv != 0ull) ? 1 : 0;
    if (tl == v) sMask = mv;
  }
  int simC = __popcll(sMask);
  const int merges = NPTS - kcnt;

  float simS = 0.f, disS = 0.f;
  #pragma unroll
  for (int j = 0; j < NPTS; ++j) {
    bool sim = (sMask >> j) & 1ull;
    simS += sim ? drow[j] : 0.f;
    disS += sim ? 0.f : drow[j];
  }

  unsigned long long same = 1ull << l;
  int repSlot = l;
  int ecnt = 0;

  #pragma unroll 1
  for (int rd = 0; rd < 6; ++rd) {
    // masked row argmin: 4 independent chains (breaks dep chain), lex merge
    float bva = BIGF, bvb = BIGF, bvc = BIGF, bvd = BIGF;
    int bja = 64, bjb = 64, bjc = 64, bjd = 64;
    #pragma unroll
    for (int j4 = 0; j4 < 16; ++j4) {
      const int j = j4 << 2;
      bool oa = !((same >> (j + 0)) & 1ull) && (drow[j + 0] < bva);
      bva = oa ? drow[j + 0] : bva; bja = oa ? j + 0 : bja;
      bool ob = !((same >> (j + 1)) & 1ull) && (drow[j + 1] < bvb);
      bvb = ob ? drow[j + 1] : bvb; bjb = ob ? j + 1 : bjb;
      bool oc = !((same >> (j + 2)) & 1ull) && (drow[j + 2] < bvc);
      bvc = oc ? drow[j + 2] : bvc; bjc = oc ? j + 2 : bjc;
      bool od = !((same >> (j + 3)) & 1ull) && (drow[j + 3] < bvd);
      bvd = od ? drow[j + 3] : bvd; bjd = od ? j + 3 : bjd;
    }
    float bv = bva; int bj = bja;
    if (bvb < bv || (bvb == bv && bjb < bj)) { bv = bvb; bj = bjb; }
    if (bvc < bv || (bvc == bv && bjc < bj)) { bv = bvc; bj = bjc; }
    if (bvd < bv || (bvd == bv && bjd < bj)) { bv = bvd; bj = bjd; }

    // per-comp min via 32-step radix ballot (exact; all comps in parallel)
    const unsigned bits = (bj < 64) ? __float_as_uint(bv) : 0xFFFFFFFFu;
    unsigned long long cand = same;
    unsigned minb = 0u;
    #pragma unroll
    for (int k = 31; k >= 0; --k) {
      unsigned long long mb = __ballot(((bits >> k) & 1u) != 0u);
      unsigned long long z = cand & ~mb;
      bool hz = (z != 0ull);
      cand = hz ? z : cand;
      minb = (minb << 1) | (hz ? 0u : 1u);
    }
    const bool valid = (minb != 0xFFFFFFFFu);
    const int wl = __ffsll((long long)cand) - 1;   // lowest lane = lowest flat

    unsigned long long bjm[6]; publish6(bj, bjm);
    const int v_wl = extract6(bjm, wl);            // winner's endpoint

    unsigned long long rpm[6]; publish6(repSlot, rpm);
    const int otherRep = extract6(rpm, v_wl);      // rep of other comp

    const bool isRoot = (l == repSlot);
    int ptr = repSlot;
    if (isRoot && valid) ptr = otherRep;

    unsigned long long pm[6]; publish6(ptr, pm);
    const int pd = extract6(pm, ptr);
    bool adder = false;
    if (isRoot && valid && ptr != l) {
      if (pd == l && l < ptr) ptr = l;             // mutual: smaller survives
      else adder = true;
    }
    const unsigned long long A = __ballot(adder);
    if (adder)
      ekey_s[ecnt + __popcll(A & ((1ull << l) - 1ull))] =
          ((unsigned long long)minb << 12) |
          (unsigned long long)((wl << 6) | v_wl);
    ecnt += (int)__popcll(A);

    // pointer doubling via ballot-gather (ballot exit)
    #pragma unroll 1
    for (int jj = 0; jj < 6; ++jj) {
      unsigned long long dm[6]; publish6(ptr, dm);
      const int p2 = extract6(dm, ptr);
      if (__ballot(p2 != ptr) == 0ull) break;
      ptr = p2;
    }
    same = match6(ptr);
    repSlot = __ffsll((long long)same) - 1;
    if (same == ~0ull) break;
  }
  lds_fence();                                     // ekey_s stores visible

  // ---- edge selection: keep the `merges` smallest (w, flat) keys ----
  const bool ehave = (l < ecnt);
  const unsigned long long my = ehave ? ekey_s[l] : ~0ull;
  int rank = 0;
  #pragma unroll 7
  for (int j = 0; j < 63; ++j) {
    unsigned long long kj = ekey_s[j];
    rank += (j < ecnt && kj < my) ? 1 : 0;
  }
  const bool kept = ehave && (rank < merges);
  const int eu = (int)((my >> 6) & 63);
  const int ev = (int)(my & 63);

  // ---- label propagation: edge relax + pointer doubling (LDS) ----
  lab_s[l] = l;
  lds_fence();
  #pragma unroll 1
  for (int iter = 0; iter < 64; ++iter) {
    int m = 0; bool ch = false;
    if (kept) {
      const int lu = lab_s[eu], lv = lab_s[ev];
      m = min(lu, lv);
      ch = (m < lu) || (m < lv);
    }
    if (ch) {
      atomicMin(&lab_s[eu], m);
      atomicMin(&lab_s[ev], m);
    }
    lds_fence();
    const int la = lab_s[l];
    const int lb = lab_s[la];
    if (lb < la) lab_s[l] = lb;
    lds_fence();
    if (__ballot(ch) == 0ull) break;
  }
  const int cl = lab_s[l];

  const unsigned long long cMask = match6(cl);
  int ec2 = __popcll(cMask ^ sMask);

  #pragma unroll
  for (int off = 32; off; off >>= 1) {
    simS += __shfl_xor(simS, off);
    disS += __shfl_xor(disS, off);
    simC += __shfl_xor(simC, off);
    ec2  += __shfl_xor(ec2, off);
  }
  if (l == 0) {
    simS_o[b] = simS; disS_o[b] = disS;
    simC_o[b] = simC; errC_o[b] = ec2;
  }
}

__global__ __launch_bounds__(64) void finalize_kernel(
    const float* __restrict__ simS, const float* __restrict__ disS,
    const int* __restrict__ simC, const int* __restrict__ errC,
    float* __restrict__ out)
{
  const int l = threadIdx.x;
  double ss = 0.0, dd = 0.0, sc = 0.0, ec = 0.0;
  #pragma unroll
  for (int r = 0; r < 4; ++r) {
    int i = (r << 6) + l;
    ss += (double)simS[i];
    dd += (double)disS[i];
    sc += (double)simC[i];
    ec += (double)errC[i];
  }
  #pragma unroll
  for (int off = 32; off; off >>= 1) {
    ss += __shfl_xor(ss, off);
    dd += __shfl_xor(dd, off);
    sc += __shfl_xor(sc, off);
    ec += __shfl_xor(ec, off);
  }
  if (l == 0) {
    const double total = 256.0 * 4096.0;
    double ms = ss / sc;
    double md = dd / (total - sc);
    out[0] = (float)(ec / 256.0 + 0.5 * (ms - md));
  }
}

extern "C" void kernel_launch(void* const* d_in, const int* in_sizes, int n_in,
                              void* d_out, int out_size, void* d_ws, size_t ws_size,
                              hipStream_t stream) {
  const float* q      = (const float*)d_in[0];
  const float* psg    = (const float*)d_in[1];
  const int*   labels = (const int*)d_in[2];
  float* out = (float*)d_out;

  float* simS = (float*)d_ws;          // [256]
  float* disS = simS + 256;            // [256]
  int*   simC = (int*)(disS + 256);    // [256]
  int*   errC = simC + 256;            // [256]

  fused_kernel<<<256, NT, 0, stream>>>(q, psg, labels, simS, disS, simC, errC);
  finalize_kernel<<<1, 64, 0, stream>>>(simS, disS, simC, errC, out);
}